// Round 2
// baseline (417.137 us; speedup 1.0000x reference)
//
#include <hip/hip_runtime.h>

// Problem constants
#define BATCH  64
#define CH     64
#define WFLAT  16384          // 128*128
#define KSPLIT 4
#define KPER   (WFLAT / KSPLIT)  // 4096
#define BK     128            // K-chunk staged in LDS per iteration
#define LDSS   136            // LDS row stride in bf16 elements (128 + 8 pad)

typedef short bf16x8 __attribute__((ext_vector_type(8)));
typedef float f32x4  __attribute__((ext_vector_type(4)));

__device__ __forceinline__ unsigned int f2bf(float f) {
  // fp32 -> bf16 bits, round-to-nearest-even; low 16 bits valid
  unsigned int u = __float_as_uint(f);
  return (u + 0x7FFFu + ((u >> 16) & 1u)) >> 16;
}

// ---------------------------------------------------------------------------
// Kernel 1: batched Gram matrices with K-split.
// grid = BATCH * KSPLIT blocks of 256 threads. Block (b, ks) computes the
// partial Gram over K range [ks*KPER, (ks+1)*KPER) and atomicAdds the scaled
// result into g[b] (g pre-zeroed by hipMemsetAsync).
// ---------------------------------------------------------------------------
__global__ __launch_bounds__(256) void gram_kernel(const float* __restrict__ x,
                                                   float* __restrict__ g) {
  const int b  = blockIdx.x & (BATCH - 1);
  const int ks = blockIdx.x >> 6;
  const float* __restrict__ xb = x + (size_t)b * CH * WFLAT + (size_t)ks * KPER;

  __shared__ unsigned short smem[CH * LDSS];   // 64 x 136 bf16 = 17408 B

  const int tid  = threadIdx.x;
  const int wave = tid >> 6;
  const int lane = tid & 63;
  const int quad = lane >> 4;
  const int l15  = lane & 15;

  f32x4 acc[4];
#pragma unroll
  for (int n = 0; n < 4; n++) acc[n] = (f32x4){0.f, 0.f, 0.f, 0.f};

  for (int k0 = 0; k0 < KPER; k0 += BK) {
    __syncthreads();  // protect previous iteration's LDS reads
    // Stage 64 rows x 128 cols fp32 -> bf16 into LDS.
    // 8192 floats = 2048 float4; 8 float4 per thread, coalesced 512B runs.
#pragma unroll
    for (int r = 0; r < 8; r++) {
      const int idx = r * 256 + tid;
      const int row = idx >> 5;        // 32 float4 per row
      const int c4  = idx & 31;
      const float4 v = *(const float4*)(xb + (size_t)row * WFLAT + k0 + c4 * 4);
      const unsigned int lo = f2bf(v.x) | (f2bf(v.y) << 16);
      const unsigned int hi = f2bf(v.z) | (f2bf(v.w) << 16);
      *(uint2*)(&smem[row * LDSS + c4 * 4]) = make_uint2(lo, hi);
    }
    __syncthreads();

    // 4 MFMA K-steps of 32 over the 128-wide chunk.
    // A-frag: A[m=lane&15][k=quad*8+j]; B-frag: B[k=quad*8+j][n=lane&15].
    // Both operands are rows of x_b (G = x x^T), so load patterns coincide.
    const int arow = (wave * 16 + l15) * LDSS;
#pragma unroll
    for (int kk = 0; kk < BK; kk += 32) {
      const int koff = kk + quad * 8;
      const bf16x8 a = *(const bf16x8*)(&smem[arow + koff]);
#pragma unroll
      for (int n = 0; n < 4; n++) {
        const bf16x8 bb = *(const bf16x8*)(&smem[(n * 16 + l15) * LDSS + koff]);
        acc[n] = __builtin_amdgcn_mfma_f32_16x16x32_bf16(a, bb, acc[n], 0, 0, 0);
      }
    }
  }

  // Epilogue: C/D mapping col=lane&15, row=quad*4+reg. Scale and merge.
  const float scale = 1.0f / ((float)CH * (float)WFLAT);
  float* gb = g + (size_t)b * CH * CH;
#pragma unroll
  for (int n = 0; n < 4; n++) {
#pragma unroll
    for (int r = 0; r < 4; r++) {
      const int row = wave * 16 + quad * 4 + r;
      const int col = n * 16 + l15;
      atomicAdd(&gb[row * CH + col], acc[n][r] * scale);
    }
  }
}

// ---------------------------------------------------------------------------
// Kernel 2: pairwise distances D[i][j] = mean((G_i - G_j)^2).
// grid = 64 blocks (one per i) of 256 threads; 4 threads per j.
// Direct difference form avoids the sq/dot cancellation.
// ---------------------------------------------------------------------------
__global__ __launch_bounds__(256) void dist_kernel(const float* __restrict__ g,
                                                   float* __restrict__ dmat) {
  const int i   = blockIdx.x;
  const int tid = threadIdx.x;
  __shared__ float4 gi4[1024];   // G_i, 16 KB

  const float4* gsrc = (const float4*)(g + (size_t)i * (CH * CH));
  for (int e = tid; e < 1024; e += 256) gi4[e] = gsrc[e];
  __syncthreads();

  const int j = tid >> 2;
  const int s = tid & 3;
  const float4* gj = (const float4*)(g + (size_t)j * (CH * CH));

  float acc = 0.f;
#pragma unroll 4
  for (int it = 0; it < 256; it++) {
    const int e = it * 4 + s;
    const float4 a = gi4[e];
    const float4 bv = gj[e];
    const float d0 = a.x - bv.x, d1 = a.y - bv.y;
    const float d2 = a.z - bv.z, d3 = a.w - bv.w;
    acc = fmaf(d0, d0, acc);
    acc = fmaf(d1, d1, acc);
    acc = fmaf(d2, d2, acc);
    acc = fmaf(d3, d3, acc);
  }
  acc += __shfl_xor(acc, 1);
  acc += __shfl_xor(acc, 2);
  if (s == 0) dmat[i * 64 + j] = acc * (1.0f / 4096.0f);
}

// ---------------------------------------------------------------------------
// Kernel 3: loss epilogue. One wave; lane i owns row i.
// Sn[i] = sum_k [t_k != t_i] exp(1 - D[i,k]);
// loss = sum_{i<j, t_i==t_j} relu(log(Sn_i+Sn_j) + D[i,j])^2 / (2P)
// NOTE: harness delivers integer inputs as int32 (NOT the reference's int64).
// ---------------------------------------------------------------------------
__global__ __launch_bounds__(64) void loss_kernel(const float* __restrict__ dmat,
                                                  const int* __restrict__ target,
                                                  float* __restrict__ out) {
  __shared__ float dsh[64 * 64];
  __shared__ int   tsh[64];
  __shared__ float snsh[64];
  const int lane = threadIdx.x;

  for (int e = lane; e < 4096; e += 64) dsh[e] = dmat[e];
  tsh[lane] = target[lane];
  __syncthreads();

  const int ti = tsh[lane];
  float sn = 0.f;
  for (int k = 0; k < 64; k++) {
    if (tsh[k] != ti) sn += expf(1.0f - dsh[lane * 64 + k]);
  }
  snsh[lane] = sn;
  __syncthreads();

  float lp = 0.f;
  int   pc = 0;
  for (int j = lane + 1; j < 64; j++) {
    if (tsh[j] == ti) {
      const float Jv = logf(sn + snsh[j]) + dsh[lane * 64 + j];
      const float r  = fmaxf(Jv, 0.f);
      lp = fmaf(r, r, lp);
      pc++;
    }
  }
#pragma unroll
  for (int off = 32; off >= 1; off >>= 1) {
    lp += __shfl_down(lp, off);
    pc += __shfl_down(pc, off);
  }
  if (lane == 0) out[0] = lp / (2.0f * (float)pc);
}

// ---------------------------------------------------------------------------
extern "C" void kernel_launch(void* const* d_in, const int* in_sizes, int n_in,
                              void* d_out, int out_size, void* d_ws, size_t ws_size,
                              hipStream_t stream) {
  const float* x      = (const float*)d_in[0];
  const int*   target = (const int*)d_in[1];   // int inputs arrive as int32
  float* out = (float*)d_out;

  float* g    = (float*)d_ws;                       // 64*64*64 fp32 = 1 MB
  float* dmat = g + (size_t)BATCH * CH * CH;        // 64*64 fp32

  // Zero the Gram accumulator (ws is poisoned 0xAA before every launch).
  hipMemsetAsync(g, 0, (size_t)BATCH * CH * CH * sizeof(float), stream);

  gram_kernel<<<BATCH * KSPLIT, 256, 0, stream>>>(x, g);
  dist_kernel<<<BATCH, 256, 0, stream>>>(g, dmat);
  loss_kernel<<<1, 64, 0, stream>>>(dmat, target, out);
}